// Round 6
// baseline (92.642 us; speedup 1.0000x reference)
//
#include <hip/hip_runtime.h>

// Problem constants (B=2, T=2048, D=1024, N_EXP=8, TOP_K=2, CAP_FACTOR=1.25)
#define N_TOK   4096
#define DDIM    1024
#define N_EXP   8
#define CAP     1280                       // floor(2*1.25*4096/8), even, >=4
#define ROW     (N_EXP * CAP)              // 10240 floats per token row
#define CB_ELEMS (N_TOK * ROW)             // 41,943,040 floats per output tensor

typedef __attribute__((ext_vector_type(4))) float f32x4;

// ws layout:
//   [0,     16384) : int  e0[4096]
//   [16384, 32768) : int  e1[4096]
//   [32768, 49152) : f32  p0[4096]
//   [49152, 65536) : f32  p1[4096]

// ---------------------------------------------------------------------------
// Kernel 1: router — 4096x8 GEMV, top-2, softmax over the 2 selected logits.
// One wave per token; lanes split D=1024 as float4 chunks. (R1/R3-proven)
// ---------------------------------------------------------------------------
__global__ __launch_bounds__(256) void router_kernel(
    const float* __restrict__ x, const float* __restrict__ wg,
    int* __restrict__ e0, int* __restrict__ e1,
    float* __restrict__ p0, float* __restrict__ p1)
{
    const int wave = threadIdx.x >> 6;
    const int lane = threadIdx.x & 63;
    const int t = blockIdx.x * 4 + wave;

    const float4* xt  = (const float4*)(x + (size_t)t * DDIM);  // 256 float4
    const float4* wg4 = (const float4*)wg;                      // [8][256]

    float acc[N_EXP];
#pragma unroll
    for (int e = 0; e < N_EXP; ++e) acc[e] = 0.f;

#pragma unroll
    for (int it = 0; it < 4; ++it) {
        const int d4 = lane + it * 64;
        const float4 xv = xt[d4];
#pragma unroll
        for (int e = 0; e < N_EXP; ++e) {
            const float4 wv = wg4[e * 256 + d4];
            acc[e] = fmaf(xv.x, wv.x,
                     fmaf(xv.y, wv.y,
                     fmaf(xv.z, wv.z,
                     fmaf(xv.w, wv.w, acc[e]))));
        }
    }

#pragma unroll
    for (int e = 0; e < N_EXP; ++e) {
#pragma unroll
        for (int off = 32; off >= 1; off >>= 1)
            acc[e] += __shfl_xor(acc[e], off, 64);
    }

    if (lane == 0) {
        // stable top-2 (strict >) matches jax.lax.top_k tie-breaking
        float v0 = -3.402823466e38f, v1 = -3.402823466e38f;
        int   i0 = 0, i1 = 0;
#pragma unroll
        for (int e = 0; e < N_EXP; ++e) {
            const float v = acc[e];
            if (v > v0)      { v1 = v0; i1 = i0; v0 = v; i0 = e; }
            else if (v > v1) { v1 = v;  i1 = e; }
        }
        const float ex  = expf(v1 - v0);
        const float inv = 1.f / (1.f + ex);
        e0[t] = i0;
        e1[t] = i1;
        p0[t] = inv;        // softmax([v0,v1])[0]
        p1[t] = ex * inv;   // softmax([v0,v1])[1]
    }
}

// ---------------------------------------------------------------------------
// Kernel 2: pure zero-fill of cb|mask (contiguous 335.5 MB) — exactly
// fillBufferAligned-shaped: per-block contiguous 320 KB chunk, f32x4 regular
// stores, no loads / no barrier / no compares, minimal VGPR.
// ---------------------------------------------------------------------------
__global__ __launch_bounds__(256) void zero_kernel(float* __restrict__ out)
{
    f32x4* dst = (f32x4*)(out + 8) + (size_t)blockIdx.x * (20 * 256);
    const f32x4 z = {0.f, 0.f, 0.f, 0.f};
#pragma unroll
    for (int it = 0; it < 20; ++it)
        dst[threadIdx.x + it * 256] = z;     // wave-iter = 4KB contiguous
}

// ---------------------------------------------------------------------------
// Kernel 3: ordered rank scan (k-major flattened order == ref cumsum order)
// + used_capacity + scatter of the ~8192 nonzero (weight, mask) entries.
// Runs AFTER the zero-fill -> kernel-boundary coherence orders the overwrite.
// 1 block, 16 waves: segment histogram -> exclusive prefix -> ballot ranks.
// (R4-proven.)
// ---------------------------------------------------------------------------
__global__ __launch_bounds__(1024) void scan_scatter_kernel(
    const int* __restrict__ e0, const int* __restrict__ e1,
    const float* __restrict__ p0, const float* __restrict__ p1,
    float* __restrict__ out)
{
    __shared__ int lds_e[2 * N_TOK];     // 32 KB
    __shared__ int seg_cnt[16][N_EXP];
    __shared__ int seg_base[16][N_EXP];

    for (int i = threadIdx.x; i < N_TOK; i += 1024) {
        lds_e[i]         = e0[i];
        lds_e[N_TOK + i] = e1[i];
    }
    __syncthreads();

    const int s    = threadIdx.x >> 6;      // segment = wave id, 512 entries
    const int lane = threadIdx.x & 63;
    const unsigned long long lt = (1ull << lane) - 1ull;

    // Phase A: per-segment per-expert counts
    int cnt[N_EXP];
#pragma unroll
    for (int ex = 0; ex < N_EXP; ++ex) cnt[ex] = 0;
#pragma unroll
    for (int c = 0; c < 8; ++c) {
        const int e = lds_e[s * 512 + c * 64 + lane];
#pragma unroll
        for (int ex = 0; ex < N_EXP; ++ex)
            cnt[ex] += __popcll(__ballot(e == ex));
    }
    if (lane == 0) {
#pragma unroll
        for (int ex = 0; ex < N_EXP; ++ex) seg_cnt[s][ex] = cnt[ex];
    }
    __syncthreads();

    // Phase B: exclusive prefix across segments; thread ex<8 owns expert ex
    if (threadIdx.x < N_EXP) {
        int run = 0;
#pragma unroll
        for (int s2 = 0; s2 < 16; ++s2) {
            seg_base[s2][threadIdx.x] = run;
            run += seg_cnt[s2][threadIdx.x];
        }
        out[threadIdx.x] = (float)min(run, CAP);   // used_capacity
    }
    __syncthreads();

    // Phase C: exact sequential ranks via ballot prefix, then scatter
    int run[N_EXP];
#pragma unroll
    for (int ex = 0; ex < N_EXP; ++ex) run[ex] = seg_base[s][ex];

    float* cb   = out + 8;
    float* mask = out + 8 + (size_t)CB_ELEMS;

#pragma unroll
    for (int c = 0; c < 8; ++c) {
        const int i = s * 512 + c * 64 + lane;
        const int e = lds_e[i];
        int myrank = CAP;                       // default: no write
#pragma unroll
        for (int ex = 0; ex < N_EXP; ++ex) {
            const unsigned long long bal = __ballot(e == ex);
            if (e == ex) myrank = run[ex] + __popcll(bal & lt);
            run[ex] += __popcll(bal);
        }
        if (myrank < CAP) {                     // dropped tokens skipped
            const int   tok = (i < N_TOK) ? i : i - N_TOK;
            const float w   = (i < N_TOK) ? p0[tok] : p1[tok];
            const size_t off = (size_t)tok * ROW + (size_t)e * CAP + myrank;
            cb[off]   = w;
            mask[off] = (w != 0.f) ? 1.f : 0.f;
        }
    }
}

// ---------------------------------------------------------------------------
extern "C" void kernel_launch(void* const* d_in, const int* in_sizes, int n_in,
                              void* d_out, int out_size, void* d_ws, size_t ws_size,
                              hipStream_t stream)
{
    const float* x  = (const float*)d_in[0];   // [2,2048,1024] f32
    const float* wg = (const float*)d_in[1];   // [8,1024] f32
    float* out = (float*)d_out;                // [8] used | cb | mask

    char*  ws = (char*)d_ws;
    int*   e0 = (int*)(ws);
    int*   e1 = (int*)(ws + 16384);
    float* p0 = (float*)(ws + 32768);
    float* p1 = (float*)(ws + 49152);

    router_kernel<<<N_TOK / 4, 256, 0, stream>>>(x, wg, e0, e1, p0, p1);
    zero_kernel<<<4096, 256, 0, stream>>>(out);
    scan_scatter_kernel<<<1, 1024, 0, stream>>>(e0, e1, p0, p1, out);
}

// Round 8
// 82.440 us; speedup vs baseline: 1.1238x; 1.1238x over previous
//
#include <hip/hip_runtime.h>

// Problem constants (B=2, T=2048, D=1024, N_EXP=8, TOP_K=2, CAP_FACTOR=1.25)
#define N_TOK   4096
#define DDIM    1024
#define N_EXP   8
#define CAP     1280                       // floor(2*1.25*4096/8), even, >=4
#define ROW     (N_EXP * CAP)              // 10240 floats per token row
#define CB_ELEMS (N_TOK * ROW)             // 41,943,040 floats per output tensor

typedef __attribute__((ext_vector_type(4))) float f32x4;

// ws layout:
//   [0,     16384) : int  e0[4096]
//   [16384, 32768) : int  e1[4096]
//   [32768, 49152) : f32  p0[4096]
//   [49152, 65536) : f32  p1[4096]
//   [65536, 98304) : int2 r01[4096]  {(e0<<16|rank0), (e1<<16|rank1)}

// ---------------------------------------------------------------------------
// Kernel 1: router — 4096x8 GEMV, top-2, softmax over the 2 selected logits.
// One wave per token; lanes split D=1024 as float4 chunks. (R1/R3-proven)
// ---------------------------------------------------------------------------
__global__ __launch_bounds__(256) void router_kernel(
    const float* __restrict__ x, const float* __restrict__ wg,
    int* __restrict__ e0, int* __restrict__ e1,
    float* __restrict__ p0, float* __restrict__ p1)
{
    const int wave = threadIdx.x >> 6;
    const int lane = threadIdx.x & 63;
    const int t = blockIdx.x * 4 + wave;

    const float4* xt  = (const float4*)(x + (size_t)t * DDIM);  // 256 float4
    const float4* wg4 = (const float4*)wg;                      // [8][256]

    float acc[N_EXP];
#pragma unroll
    for (int e = 0; e < N_EXP; ++e) acc[e] = 0.f;

#pragma unroll
    for (int it = 0; it < 4; ++it) {
        const int d4 = lane + it * 64;
        const float4 xv = xt[d4];
#pragma unroll
        for (int e = 0; e < N_EXP; ++e) {
            const float4 wv = wg4[e * 256 + d4];
            acc[e] = fmaf(xv.x, wv.x,
                     fmaf(xv.y, wv.y,
                     fmaf(xv.z, wv.z,
                     fmaf(xv.w, wv.w, acc[e]))));
        }
    }

#pragma unroll
    for (int e = 0; e < N_EXP; ++e) {
#pragma unroll
        for (int off = 32; off >= 1; off >>= 1)
            acc[e] += __shfl_xor(acc[e], off, 64);
    }

    if (lane == 0) {
        // stable top-2 (strict >) matches jax.lax.top_k tie-breaking
        float v0 = -3.402823466e38f, v1 = -3.402823466e38f;
        int   i0 = 0, i1 = 0;
#pragma unroll
        for (int e = 0; e < N_EXP; ++e) {
            const float v = acc[e];
            if (v > v0)      { v1 = v0; i1 = i0; v0 = v; i0 = e; }
            else if (v > v1) { v1 = v;  i1 = e; }
        }
        const float ex  = expf(v1 - v0);
        const float inv = 1.f / (1.f + ex);
        e0[t] = i0;
        e1[t] = i1;
        p0[t] = inv;        // softmax([v0,v1])[0]
        p1[t] = ex * inv;   // softmax([v0,v1])[1]
    }
}

// ---------------------------------------------------------------------------
// Kernel 2: ordered rank scan (k-major flattened order == ref cumsum order).
// 1 block, 16 waves: segment histogram -> exclusive prefix -> ballot ranks.
// Outputs packed (e<<16|rank) per (token,k) and used_capacity. (R3-proven)
// ---------------------------------------------------------------------------
__global__ __launch_bounds__(1024) void scan_kernel(
    const int* __restrict__ e0, const int* __restrict__ e1,
    int2* __restrict__ r01, float* __restrict__ out)
{
    __shared__ int lds_e[2 * N_TOK];     // 32 KB
    __shared__ int seg_cnt[16][N_EXP];
    __shared__ int seg_base[16][N_EXP];

    for (int i = threadIdx.x; i < N_TOK; i += 1024) {
        lds_e[i]         = e0[i];
        lds_e[N_TOK + i] = e1[i];
    }
    __syncthreads();

    const int s    = threadIdx.x >> 6;      // segment = wave id, 512 entries
    const int lane = threadIdx.x & 63;
    const unsigned long long lt = (1ull << lane) - 1ull;

    // Phase A: per-segment per-expert counts
    int cnt[N_EXP];
#pragma unroll
    for (int ex = 0; ex < N_EXP; ++ex) cnt[ex] = 0;
#pragma unroll
    for (int c = 0; c < 8; ++c) {
        const int e = lds_e[s * 512 + c * 64 + lane];
#pragma unroll
        for (int ex = 0; ex < N_EXP; ++ex)
            cnt[ex] += __popcll(__ballot(e == ex));
    }
    if (lane == 0) {
#pragma unroll
        for (int ex = 0; ex < N_EXP; ++ex) seg_cnt[s][ex] = cnt[ex];
    }
    __syncthreads();

    // Phase B: exclusive prefix across segments; thread ex<8 owns expert ex
    if (threadIdx.x < N_EXP) {
        int run = 0;
#pragma unroll
        for (int s2 = 0; s2 < 16; ++s2) {
            seg_base[s2][threadIdx.x] = run;
            run += seg_cnt[s2][threadIdx.x];
        }
        out[threadIdx.x] = (float)min(run, CAP);   // used_capacity
    }
    __syncthreads();

    // Phase C: exact sequential ranks via ballot prefix; pack (e<<16|rank)
    int run[N_EXP];
#pragma unroll
    for (int ex = 0; ex < N_EXP; ++ex) run[ex] = seg_base[s][ex];

#pragma unroll
    for (int c = 0; c < 8; ++c) {
        const int i = s * 512 + c * 64 + lane;
        const int e = lds_e[i];
        int myrank = 0;
#pragma unroll
        for (int ex = 0; ex < N_EXP; ++ex) {
            const unsigned long long bal = __ballot(e == ex);
            if (e == ex) myrank = run[ex] + __popcll(bal & lt);
            run[ex] += __popcll(bal);
        }
        const int er = (e << 16) | myrank;          // rank <= 8191, fits
        if (i < N_TOK) r01[i].x = er;
        else           r01[i - N_TOK].y = er;
    }
}

// ---------------------------------------------------------------------------
// Kernel 3: fill — ONE CONTIGUOUS 80 KB STREAM PER BLOCK.
// Blocks [0,2048): zero cb rows of token pair (2b, 2b+1), then fix up <=4
// cb entries (L2-warm). Blocks [2048,4096): same for mask rows.
// Contiguity matches fillBufferAligned's access shape; fixups stay warm.
// ---------------------------------------------------------------------------
__global__ __launch_bounds__(256) void fill_kernel(
    const int2* __restrict__ r01, const float* __restrict__ p0,
    const float* __restrict__ p1, float* __restrict__ out)
{
    const int  b     = blockIdx.x;
    const bool is_cb = (b < 2048);
    const int  t0    = is_cb ? (b * 2) : ((b - 2048) * 2);   // token pair base

    float* base = out + 8 + (is_cb ? 0 : (size_t)CB_ELEMS) + (size_t)t0 * ROW;
    f32x4* b4   = (f32x4*)base;                  // 5120 f32x4 = 80 KB contiguous
    const f32x4 z = {0.f, 0.f, 0.f, 0.f};

#pragma unroll
    for (int it = 0; it < 20; ++it)
        b4[threadIdx.x + it * 256] = z;

    __syncthreads();                             // vmcnt(0)+barrier: zeros done

    if (threadIdx.x < 4) {                       // 2 tokens x 2 slots
        const int  tt = t0 + (threadIdx.x >> 1); // token
        const int2 rr = r01[tt];
        const int  er = (threadIdx.x & 1) ? rr.y : rr.x;
        const int  r  = er & 0xFFFF;
        const int  e  = er >> 16;
        if (r < CAP) {                           // dropped tokens skipped
            const float w = (threadIdx.x & 1) ? p1[tt] : p0[tt];
            const float v = is_cb ? w : ((w != 0.f) ? 1.f : 0.f);
            base[(size_t)(tt - t0) * ROW + e * CAP + r] = v;
        }
    }
}

// ---------------------------------------------------------------------------
extern "C" void kernel_launch(void* const* d_in, const int* in_sizes, int n_in,
                              void* d_out, int out_size, void* d_ws, size_t ws_size,
                              hipStream_t stream)
{
    const float* x  = (const float*)d_in[0];   // [2,2048,1024] f32
    const float* wg = (const float*)d_in[1];   // [8,1024] f32
    float* out = (float*)d_out;                // [8] used | cb | mask

    char*  ws  = (char*)d_ws;
    int*   e0  = (int*)(ws);
    int*   e1  = (int*)(ws + 16384);
    float* p0  = (float*)(ws + 32768);
    float* p1  = (float*)(ws + 49152);
    int2*  r01 = (int2*)(ws + 65536);

    router_kernel<<<N_TOK / 4, 256, 0, stream>>>(x, wg, e0, e1, p0, p1);
    scan_kernel<<<1, 1024, 0, stream>>>(e0, e1, r01, out);
    fill_kernel<<<4096, 256, 0, stream>>>(r01, p0, p1, out);
}

// Round 9
// 75.781 us; speedup vs baseline: 1.2225x; 1.0879x over previous
//
#include <hip/hip_runtime.h>

// Problem constants (B=2, T=2048, D=1024, N_EXP=8, TOP_K=2, CAP_FACTOR=1.25)
#define N_TOK   4096
#define DDIM    1024
#define N_EXP   8
#define CAP     1280                       // floor(2*1.25*4096/8), even, >=4
#define ROW     (N_EXP * CAP)              // 10240 floats per token row
#define CB_ELEMS (N_TOK * ROW)             // 41,943,040 floats per output tensor

typedef __attribute__((ext_vector_type(4))) float f32x4;

// ws layout:
//   [0,     4096)  : uint  pk[1024]   packed 4-bit expert ids, entry-major:
//                    entry i = k*4096 + t -> nibble (i&7) of word (i>>3)
//   [4096,  20480) : f32   p0[4096]   softmax weight, slot k=0
//   [20480, 36864) : f32   p1[4096]   softmax weight, slot k=1

// ---------------------------------------------------------------------------
// Kernel 1: router — 4096x8 GEMV, top-2, softmax over the 2 selected logits.
// One wave per token (4/block). Each block non-atomically stores its 4 tokens'
// expert nibbles as two 16-bit halfwords (disjoint across blocks).
// ---------------------------------------------------------------------------
__global__ __launch_bounds__(256) void router_kernel(
    const float* __restrict__ x, const float* __restrict__ wg,
    unsigned int* __restrict__ pk,
    float* __restrict__ p0, float* __restrict__ p1)
{
    __shared__ int se0[4], se1[4];
    const int wave = threadIdx.x >> 6;
    const int lane = threadIdx.x & 63;
    const int t = blockIdx.x * 4 + wave;

    const float4* xt  = (const float4*)(x + (size_t)t * DDIM);  // 256 float4
    const float4* wg4 = (const float4*)wg;                      // [8][256]

    float acc[N_EXP];
#pragma unroll
    for (int e = 0; e < N_EXP; ++e) acc[e] = 0.f;

#pragma unroll
    for (int it = 0; it < 4; ++it) {
        const int d4 = lane + it * 64;
        const float4 xv = xt[d4];
#pragma unroll
        for (int e = 0; e < N_EXP; ++e) {
            const float4 wv = wg4[e * 256 + d4];
            acc[e] = fmaf(xv.x, wv.x,
                     fmaf(xv.y, wv.y,
                     fmaf(xv.z, wv.z,
                     fmaf(xv.w, wv.w, acc[e]))));
        }
    }

#pragma unroll
    for (int e = 0; e < N_EXP; ++e) {
#pragma unroll
        for (int off = 32; off >= 1; off >>= 1)
            acc[e] += __shfl_xor(acc[e], off, 64);
    }

    if (lane == 0) {
        // stable top-2 (strict >) matches jax.lax.top_k tie-breaking
        float v0 = -3.402823466e38f, v1 = -3.402823466e38f;
        int   i0 = 0, i1 = 0;
#pragma unroll
        for (int e = 0; e < N_EXP; ++e) {
            const float v = acc[e];
            if (v > v0)      { v1 = v0; i1 = i0; v0 = v; i0 = e; }
            else if (v > v1) { v1 = v;  i1 = e; }
        }
        const float ex  = expf(v1 - v0);
        const float inv = 1.f / (1.f + ex);
        p0[t] = inv;        // softmax([v0,v1])[0]
        p1[t] = ex * inv;   // softmax([v0,v1])[1]
        se0[wave] = i0;
        se1[wave] = i1;
    }
    __syncthreads();

    if (threadIdx.x == 0) {
        const int b = blockIdx.x;
        unsigned short* pks = (unsigned short*)pk;
        const unsigned short h0 = (unsigned short)(se0[0] | (se0[1] << 4) |
                                                   (se0[2] << 8) | (se0[3] << 12));
        const unsigned short h1 = (unsigned short)(se1[0] | (se1[1] << 4) |
                                                   (se1[2] << 8) | (se1[3] << 12));
        pks[b]        = h0;   // k=0 entries 4b..4b+3
        pks[1024 + b] = h1;   // k=1 entries 4096+4b..4096+4b+3
    }
}

// ---------------------------------------------------------------------------
// Kernel 2: fill — one contiguous 80 KB chunk per block (R8-proven shape).
// Each block redundantly recomputes the exact k-major prefix ranks for its
// own <=4 entries from the 4 KB packed-expert array (L2-hot broadcast),
// hidden under its streaming zero stores. Block 0 also emits used_capacity.
// Blocks [0,2048): cb rows of tokens (2b,2b+1); [2048,4096): mask rows.
// ---------------------------------------------------------------------------
__global__ __launch_bounds__(256) void fill_kernel(
    const unsigned int* __restrict__ pk, const float* __restrict__ p0,
    const float* __restrict__ p1, float* __restrict__ out)
{
    __shared__ unsigned int spk[1024];   // 4 KB packed expert ids
    __shared__ int s_e[4], s_r[4];

    const int  b     = blockIdx.x;
    const bool is_cb = (b < 2048);
    const int  t0    = (is_cb ? b : (b - 2048)) * 2;   // token pair base

    float* base = out + 8 + (is_cb ? 0 : (size_t)CB_ELEMS) + (size_t)t0 * ROW;
    f32x4* b4   = (f32x4*)base;                  // 5120 f32x4 = 80 KB contiguous
    const f32x4 z = {0.f, 0.f, 0.f, 0.f};

    // issue the zero stores first; they drain while we scan
#pragma unroll
    for (int it = 0; it < 20; ++it)
        b4[threadIdx.x + it * 256] = z;

#pragma unroll
    for (int j = 0; j < 4; ++j)
        spk[threadIdx.x + j * 256] = pk[threadIdx.x + j * 256];
    __syncthreads();                             // spk visible (stores also drained)

    const int wave = threadIdx.x >> 6;
    const int lane = threadIdx.x & 63;

    // wave w -> entry (token t0+(w>>1), slot w&1); rank = # prior entries, same e
    const int tt = t0 + (wave >> 1);
    const int i  = (wave & 1) * N_TOK + tt;
    const int e  = (spk[i >> 3] >> ((i & 7) * 4)) & 0xF;

    int cnt = 0;
    for (int j = 0; j < 16; ++j) {
        const unsigned int w  = spk[lane + j * 64];   // stride-64 words: 2-way bank, free
        const int          bi = (lane + j * 64) * 8;  // global entry index of nibble 0
#pragma unroll
        for (int s = 0; s < 8; ++s)
            cnt += (bi + s < i && (int)((w >> (4 * s)) & 0xF) == e) ? 1 : 0;
    }
#pragma unroll
    for (int off = 32; off >= 1; off >>= 1)
        cnt += __shfl_xor(cnt, off, 64);

    if (lane == 0) { s_e[wave] = e; s_r[wave] = cnt; }
    __syncthreads();                             // vmcnt(0): zeros done; ranks visible

    if (threadIdx.x < 4) {
        const int r = s_r[threadIdx.x];
        if (r < CAP) {                           // dropped tokens (rank>=cap) skipped
            const int   tt2 = t0 + (threadIdx.x >> 1);
            const float w   = (threadIdx.x & 1) ? p1[tt2] : p0[tt2];
            const float v   = is_cb ? w : ((w != 0.f) ? 1.f : 0.f);
            base[(size_t)(tt2 - t0) * ROW + s_e[threadIdx.x] * CAP + r] = v;
        }
    }

    // block 0: used_capacity[8] = min(total per expert, CAP)
    if (b == 0) {
        for (int ee = wave * 2; ee < wave * 2 + 2; ++ee) {
            int c = 0;
            for (int j = 0; j < 16; ++j) {
                const unsigned int w = spk[lane + j * 64];
#pragma unroll
                for (int s = 0; s < 8; ++s)
                    c += ((int)((w >> (4 * s)) & 0xF) == ee) ? 1 : 0;
            }
#pragma unroll
            for (int off = 32; off >= 1; off >>= 1)
                c += __shfl_xor(c, off, 64);
            if (lane == 0) out[ee] = (float)min(c, CAP);
        }
    }
}

// ---------------------------------------------------------------------------
extern "C" void kernel_launch(void* const* d_in, const int* in_sizes, int n_in,
                              void* d_out, int out_size, void* d_ws, size_t ws_size,
                              hipStream_t stream)
{
    const float* x  = (const float*)d_in[0];   // [2,2048,1024] f32
    const float* wg = (const float*)d_in[1];   // [8,1024] f32
    float* out = (float*)d_out;                // [8] used | cb | mask

    char*         ws = (char*)d_ws;
    unsigned int* pk = (unsigned int*)(ws);
    float*        p0 = (float*)(ws + 4096);
    float*        p1 = (float*)(ws + 20480);

    router_kernel<<<N_TOK / 4, 256, 0, stream>>>(x, wg, pk, p0, p1);
    fill_kernel<<<4096, 256, 0, stream>>>(pk, p0, p1, out);
}